// Round 1
// baseline (23.968 us; speedup 1.0000x reference)
//
#include <hip/hip_runtime.h>
#include <math.h>

// Problem constants
#define B   32
#define P   1024
#define DX  5
#define BP  (B * P)            // 32768 particles
#define LIKE_OFF (BP * DX)     // offset of `like` in flat d_out (163840)

// new_state depends only on `particles` + pr1/pr2/pr3 weights.
// like == 1/1024 exactly (normalization of P identical values).

__global__ __launch_bounds__(256) void particle_kernel(
    const float* __restrict__ particles,   // (B*P, 5)
    const float* __restrict__ pr1_w,       // (2, 32)
    const float* __restrict__ pr1_b,       // (32,)
    const float* __restrict__ pr2_w,       // (32, 64)
    const float* __restrict__ pr2_b,       // (64,)
    const float* __restrict__ pr3_w,       // (64, 2)
    const float* __restrict__ pr3_b,       // (2,)
    float* __restrict__ out)               // [BP*5 new_state | BP like]
{
    __shared__ __align__(16) float sW1[2 * 32];
    __shared__ __align__(16) float sB1[32];
    __shared__ __align__(16) float sW2[32 * 64];
    __shared__ __align__(16) float sB2[64];
    __shared__ __align__(16) float sW3[64 * 2];
    __shared__ __align__(16) float sB3[2];

    const int t = threadIdx.x;

    // Cooperative staging of all pr-weights into LDS (~9.4 KB)
    if (t < 64)  sW1[t] = pr1_w[t];
    if (t < 32)  sB1[t] = pr1_b[t];
    for (int i = t; i < 32 * 64; i += 256) sW2[i] = pr2_w[i];
    if (t < 64)  sB2[t] = pr2_b[t];
    if (t < 128) sW3[t] = pr3_w[t];
    if (t < 2)   sB3[t] = pr3_b[t];
    __syncthreads();

    const int idx = blockIdx.x * 256 + t;   // particle index, 0..BP-1 exactly

    // Load particle state (5 consecutive floats)
    const float* s = particles + idx * DX;
    const float s0 = s[0];
    const float s1 = s[1];
    const float s2 = s[2];
    const float v  = s[3];
    const float td = s[4];

    const float theta = s2 + td;
    const float x = s0 + v * sinf(theta);
    const float y = s1 + v * cosf(theta);

    // Layer 1: din(2) @ (2,32) + b, relu
    float h1[32];
#pragma unroll
    for (int j = 0; j < 32; ++j) {
        float a = fmaf(v, sW1[j], fmaf(td, sW1[32 + j], sB1[j]));
        h1[j] = fmaxf(a, 0.0f);
    }

    // Layer 2: h1(32) @ (32,64) + b, relu — float4 LDS reads (wave-uniform broadcast)
    float h2[64];
    const float4* W2v = reinterpret_cast<const float4*>(sW2);
    const float4* B2v = reinterpret_cast<const float4*>(sB2);
#pragma unroll
    for (int j4 = 0; j4 < 16; ++j4) {
        float4 acc = B2v[j4];
#pragma unroll
        for (int k = 0; k < 32; ++k) {
            float4 w = W2v[k * 16 + j4];
            acc.x = fmaf(h1[k], w.x, acc.x);
            acc.y = fmaf(h1[k], w.y, acc.y);
            acc.z = fmaf(h1[k], w.z, acc.z);
            acc.w = fmaf(h1[k], w.w, acc.w);
        }
        h2[j4 * 4 + 0] = fmaxf(acc.x, 0.0f);
        h2[j4 * 4 + 1] = fmaxf(acc.y, 0.0f);
        h2[j4 * 4 + 2] = fmaxf(acc.z, 0.0f);
        h2[j4 * 4 + 3] = fmaxf(acc.w, 0.0f);
    }

    // Layer 3: h2(64) @ (64,2) + b, tanh
    float u0 = sB3[0], u1 = sB3[1];
#pragma unroll
    for (int k = 0; k < 64; ++k) {
        u0 = fmaf(h2[k], sW3[k * 2 + 0], u0);
        u1 = fmaf(h2[k], sW3[k * 2 + 1], u1);
    }
    u0 = tanhf(u0);
    u1 = tanhf(u1);

    // new_state = [x, y, theta, v + u0, td + u1]
    float* o = out + idx * DX;
    o[0] = x;
    o[1] = y;
    o[2] = theta;
    o[3] = v + u0;
    o[4] = td + u1;

    // like[b, p] = 1/P exactly (sigmoid value cancels in normalization)
    out[LIKE_OFF + idx] = 1.0f / 1024.0f;
}

extern "C" void kernel_launch(void* const* d_in, const int* in_sizes, int n_in,
                              void* d_out, int out_size, void* d_ws, size_t ws_size,
                              hipStream_t stream) {
    // setup_inputs() order:
    //  0 image, 1 particles, 2 w1, 3 b1, 4 w2, 5 b2, 6 w3, 7 b3, 8 w4, 9 b4,
    // 10 w5, 11 b5, 12 fc1_w, 13 fc1_b, 14 fc2_w, 15 fc2_b, 16 fc4_w, 17 fc4_b,
    // 18 lk1_w, 19 lk1_b, 20 lk2_w, 21 lk2_b, 22 lk3_w, 23 lk3_b,
    // 24 pr1_w, 25 pr1_b, 26 pr2_w, 27 pr2_b, 28 pr3_w, 29 pr3_b
    const float* particles = (const float*)d_in[1];
    const float* pr1_w = (const float*)d_in[24];
    const float* pr1_b = (const float*)d_in[25];
    const float* pr2_w = (const float*)d_in[26];
    const float* pr2_b = (const float*)d_in[27];
    const float* pr3_w = (const float*)d_in[28];
    const float* pr3_b = (const float*)d_in[29];
    float* out = (float*)d_out;

    dim3 grid(BP / 256);   // 128 blocks
    dim3 block(256);
    particle_kernel<<<grid, block, 0, stream>>>(
        particles, pr1_w, pr1_b, pr2_w, pr2_b, pr3_w, pr3_b, out);
}

// Round 2
// 21.219 us; speedup vs baseline: 1.1296x; 1.1296x over previous
//
#include <hip/hip_runtime.h>
#include <math.h>

// Problem constants
#define B   32
#define P   1024
#define DX  5
#define BP  (B * P)            // 32768 particles
#define LIKE_OFF (BP * DX)     // offset of `like` in flat d_out (163840)

// Dataflow analysis (verified R0): new_state depends only on particles +
// pr1/pr2/pr3; like == 1/1024 exactly (P identical rows normalize away).
//
// R1 change: all weight reads are wave-uniform with compile-time-constant
// indices -> compiler emits s_load into SGPRs, FMAs consume the SGPR operand
// directly (v_fma_f32 v, s, v). No LDS, no barriers. 256 blocks so every CU
// is busy (R0 used 128 blocks = half the GPU idle, LDS-throughput bound).

__device__ __forceinline__ float fast_tanh(float x) {
    // tanh(x) = (e^{2x}-1)/(e^{2x}+1); clamp so __expf can't overflow.
    x = fminf(fmaxf(x, -15.0f), 15.0f);
    float e = __expf(2.0f * x);
    return (e - 1.0f) / (e + 1.0f);
}

__global__ __launch_bounds__(128) void particle_kernel(
    const float* __restrict__ particles,   // (B*P, 5)
    const float* __restrict__ pr1_w,       // (2, 32)
    const float* __restrict__ pr1_b,       // (32,)
    const float* __restrict__ pr2_w,       // (32, 64)
    const float* __restrict__ pr2_b,       // (64,)
    const float* __restrict__ pr3_w,       // (64, 2)
    const float* __restrict__ pr3_b,       // (2,)
    float* __restrict__ out)               // [BP*5 new_state | BP like]
{
    const int idx = blockIdx.x * 128 + threadIdx.x;   // 0..BP-1 exactly

    // Per-particle state: 5 consecutive floats (coalesced across the wave)
    const float* s = particles + idx * DX;
    const float s0 = s[0];
    const float s1 = s[1];
    const float s2 = s[2];
    const float v  = s[3];
    const float td = s[4];

    const float theta = s2 + td;
    const float x = fmaf(v, __sinf(theta), s0);
    const float y = fmaf(v, __cosf(theta), s1);

    // Layer 1: din(2) @ (2,32) + b, relu — weights via scalar loads
    float h1[32];
#pragma unroll
    for (int j = 0; j < 32; ++j) {
        float a = fmaf(v, pr1_w[j], fmaf(td, pr1_w[32 + j], pr1_b[j]));
        h1[j] = fmaxf(a, 0.0f);
    }

    // Layer 2: h1(32) @ (32,64) + b, relu — 2048 v_fma with SGPR weight operand
    float acc[64];
#pragma unroll
    for (int j = 0; j < 64; ++j) acc[j] = pr2_b[j];
#pragma unroll
    for (int k = 0; k < 32; ++k) {
        const float hk = h1[k];
#pragma unroll
        for (int j = 0; j < 64; ++j) {
            acc[j] = fmaf(hk, pr2_w[k * 64 + j], acc[j]);
        }
    }

    // Layer 3: relu(h2)(64) @ (64,2) + b, tanh
    float u0 = pr3_b[0];
    float u1 = pr3_b[1];
#pragma unroll
    for (int j = 0; j < 64; ++j) {
        const float h2 = fmaxf(acc[j], 0.0f);
        u0 = fmaf(h2, pr3_w[2 * j + 0], u0);
        u1 = fmaf(h2, pr3_w[2 * j + 1], u1);
    }
    u0 = fast_tanh(u0);
    u1 = fast_tanh(u1);

    // new_state = [x, y, theta, v + u0, td + u1]
    float* o = out + idx * DX;
    o[0] = x;
    o[1] = y;
    o[2] = theta;
    o[3] = v + u0;
    o[4] = td + u1;

    // like[b, p] = 1/P exactly
    out[LIKE_OFF + idx] = 1.0f / 1024.0f;
}

extern "C" void kernel_launch(void* const* d_in, const int* in_sizes, int n_in,
                              void* d_out, int out_size, void* d_ws, size_t ws_size,
                              hipStream_t stream) {
    // setup_inputs() order:
    //  0 image, 1 particles, ..., 24 pr1_w, 25 pr1_b, 26 pr2_w, 27 pr2_b,
    // 28 pr3_w, 29 pr3_b
    const float* particles = (const float*)d_in[1];
    const float* pr1_w = (const float*)d_in[24];
    const float* pr1_b = (const float*)d_in[25];
    const float* pr2_w = (const float*)d_in[26];
    const float* pr2_b = (const float*)d_in[27];
    const float* pr3_w = (const float*)d_in[28];
    const float* pr3_b = (const float*)d_in[29];
    float* out = (float*)d_out;

    dim3 grid(BP / 128);   // 256 blocks -> one per CU, all CUs active
    dim3 block(128);
    particle_kernel<<<grid, block, 0, stream>>>(
        particles, pr1_w, pr1_b, pr2_w, pr2_b, pr3_w, pr3_b, out);
}